// Round 9
// baseline (129.500 us; speedup 1.0000x reference)
//
#include <hip/hip_runtime.h>
#include <hip/hip_bf16.h>

// Problem constants (hardcoded from setup_inputs; n_shifts == T == 64)
#define NB   4096
#define NT   64
#define NDIM 16
#define NH1  256
#define NH2  256
#define NLAT 64
#define NKD  80
#define YROW (NT * NKD)      // 5120 floats per batch row of y / y_pred
#define KTAB 98304           // short-offset of K-power fragment table in ws
#define KSLOT 15360          // shorts per t-slot (7680 hi + 7680 lo)

// kpow frag-image geometry: hi at [row][0..79], lo at [row][96..175]
#define FROW 184
#define FIMG_B (80 * FROW * 2)   // 29440 bytes per image

typedef __attribute__((ext_vector_type(8)))  short bf16x8;
typedef __attribute__((ext_vector_type(4)))  float f32x4;
typedef __attribute__((ext_vector_type(16))) float f32x16;

#define MFMA   __builtin_amdgcn_mfma_f32_16x16x32_bf16
#define MFMA32 __builtin_amdgcn_mfma_f32_32x32x16_bf16

static __device__ __forceinline__ short f2bf(float f) {
  union { float f; unsigned u; } v; v.f = f;
  unsigned r = v.u + 0x7fffu + ((v.u >> 16) & 1u);   // RNE
  return (short)(r >> 16);
}
static __device__ __forceinline__ float bf2f(short h) {
  union { unsigned u; float f; } v; v.u = ((unsigned)(unsigned short)h) << 16;
  return v.f;
}
static __device__ __forceinline__ bf16x8 pack8(float4 a, float4 b) {
  bf16x8 r;
  r[0] = f2bf(a.x); r[1] = f2bf(a.y); r[2] = f2bf(a.z); r[3] = f2bf(a.w);
  r[4] = f2bf(b.x); r[5] = f2bf(b.y); r[6] = f2bf(b.z); r[7] = f2bf(b.w);
  return r;
}
static __device__ __forceinline__ void split8(float4 v0, float4 v1, bf16x8& h, bf16x8& l) {
  h = pack8(v0, v1);
  float4 r0, r1;
  r0.x = v0.x - bf2f(h[0]); r0.y = v0.y - bf2f(h[1]);
  r0.z = v0.z - bf2f(h[2]); r0.w = v0.w - bf2f(h[3]);
  r1.x = v1.x - bf2f(h[4]); r1.y = v1.y - bf2f(h[5]);
  r1.z = v1.z - bf2f(h[6]); r1.w = v1.w - bf2f(h[7]);
  l = pack8(r0, r1);
}

// ---------------------------------------------------------------------------
// Prep v2: 32-row MFMA A-fragments for mfma_f32_32x32x16_bf16.
// A-frag: lane l holds W[g][k], g = mt*32 + (l&31), k = kstep*16 + (l>>5)*8 + e.
// ws (shorts): [0) W2f 65536 = [16 kstep][8 mt][64 lane][8 e]
//              [65536) W3f 16384 = [16 kstep][2 mt][512]
//              [81920) W1f 4096  = [8 mt][512]   (K=16, single kstep)
// K-power hi/lo fragment table at KTAB (written by kpow; 16x16 shape).
// ---------------------------------------------------------------------------
__global__ __launch_bounds__(256) void prep_kernel(const float* __restrict__ W1,
                                                   const float* __restrict__ W2,
                                                   const float* __restrict__ W3,
                                                   short* __restrict__ ws) {
  int i = blockIdx.x * 256 + threadIdx.x;   // 0..65535
  {
    int e = i & 7, l = (i >> 3) & 63, mt = (i >> 9) & 7, kk = i >> 12;
    int g = mt * 32 + (l & 31);
    int k = kk * 16 + (l >> 5) * 8 + e;
    ws[i] = f2bf(W2[g * NH1 + k]);
  }
  if (i < 16384) {
    int e = i & 7, l = (i >> 3) & 63, mt = (i >> 9) & 1, kk = i >> 10;
    int g = mt * 32 + (l & 31);
    int k = kk * 16 + (l >> 5) * 8 + e;
    ws[65536 + i] = f2bf(W3[g * NH2 + k]);
  }
  if (i < 4096) {
    int e = i & 7, l = (i >> 3) & 63, mt = i >> 9;
    int g = mt * 32 + (l & 31);
    int k = (l >> 5) * 8 + e;                      // 0..15, all valid
    ws[81920 + i] = f2bf(W1[g * NDIM + k]);
  }
}

// ---------------------------------------------------------------------------
// kpow v3 (unchanged, proven ~5 us): binary exponentiation with the running
// power kept as PRE-SPLIT hi/lo bf16 frag images in both orientations.
// ---------------------------------------------------------------------------
__global__ void kpow_kernel(const float* __restrict__ Kg, short* __restrict__ ws) {
  extern __shared__ char smem[];
  short* kA   = (short*)smem;
  short* curA = (short*)(smem + FIMG_B);
  short* curB = (short*)(smem + 2 * FIMG_B);
  short* nxtA = (short*)(smem + 3 * FIMG_B);
  short* nxtB = (short*)(smem + 4 * FIMG_B);

  const int tid  = threadIdx.x;
  const int lane = tid & 63;
  const int w    = tid >> 6;
  const int l15  = lane & 15;
  const int kg   = lane >> 4;
  const int t    = blockIdx.x + 1;          // 1..63

  for (int i = tid; i < 6400; i += 512) {
    float v = Kg[i];
    int r = i / 80, c = i - r * 80;
    short hi = f2bf(v);
    short lo = f2bf(v - bf2f(hi));
    kA[r * FROW + c] = hi;        kA[r * FROW + 96 + c] = lo;
    curA[r * FROW + c] = hi;      curA[r * FROW + 96 + c] = lo;
    curB[c * FROW + r] = hi;      curB[c * FROW + 96 + r] = lo;
  }
  __syncthreads();

  auto mm = [&](const short* Ai, const short* Bi, short* DA, short* DB) {
    for (int id = w; id < 25; id += 8) {
      const int mt = id / 5, nt = id % 5;
      f32x4 acc = {0.f, 0.f, 0.f, 0.f};
#pragma unroll
      for (int kk = 0; kk < 3; ++kk) {
        const int k0 = kk * 32 + kg * 8;
        bf16x8 ah = {}, al = {}, bh = {}, bl = {};
        if (k0 < 80) {
          const short* ap = Ai + (mt * 16 + l15) * FROW + k0;
          const short* bp = Bi + (nt * 16 + l15) * FROW + k0;
          ah = *(const bf16x8*)ap;  al = *(const bf16x8*)(ap + 96);
          bh = *(const bf16x8*)bp;  bl = *(const bf16x8*)(bp + 96);
        }
        acc = MFMA(ah, bh, acc, 0, 0, 0);
        acc = MFMA(al, bh, acc, 0, 0, 0);
        acc = MFMA(ah, bl, acc, 0, 0, 0);
      }
      const int n = nt * 16 + l15;
      const int rowb = mt * 16 + kg * 4;
      short4 hs, ls;
#pragma unroll
      for (int r = 0; r < 4; ++r) {
        float v = acc[r];
        short hi = f2bf(v);
        short lo = f2bf(v - bf2f(hi));
        DA[(rowb + r) * FROW + n] = hi;
        DA[(rowb + r) * FROW + 96 + n] = lo;
        ((short*)&hs)[r] = hi;
        ((short*)&ls)[r] = lo;
      }
      *(short4*)(DB + n * FROW + rowb) = hs;
      *(short4*)(DB + n * FROW + 96 + rowb) = ls;
    }
    __syncthreads();
  };

  const int h = 31 - __clz(t);
  for (int bit = h - 1; bit >= 0; --bit) {
    mm(curA, curB, nxtA, nxtB);                               // square
    { short* p;
      p = curA; curA = nxtA; nxtA = p;
      p = curB; curB = nxtB; nxtB = p; }
    if ((t >> bit) & 1) {
      mm(kA, curB, nxtA, nxtB);                               // K * cur
      { short* p;
        p = curA; curA = nxtA; nxtA = p;
        p = curB; curB = nxtB; nxtB = p; }
    }
  }

  short* kt = ws + KTAB + t * KSLOT;
  for (int s = tid; s < 960; s += 512) {
    int f = s >> 6, ln = s & 63;            // f = kk*5 + nt
    int kk = f / 5, nt = f % 5;
    int k0 = kk * 32 + (ln >> 4) * 8;
    int n  = nt * 16 + (ln & 15);
    bf16x8 h8 = {}, l8 = {};
    if (k0 < 80) {
      const short* ap = curA + n * FROW + k0;
      h8 = *(const bf16x8*)ap;
      l8 = *(const bf16x8*)(ap + 96);
    }
    *(bf16x8*)(kt + f * 512 + ln * 8) = h8;
    *(bf16x8*)(kt + 7680 + f * 512 + ln * 8) = l8;
  }
}

// ---------------------------------------------------------------------------
// MLP v6: 32x32x16 MFMA. One block = one batch row (64 tokens), 4 waves.
// D = W x act^T; D col = token (lane&31), row = (reg&3)+8*(reg>>2)+4*(lane>>5)
// (HW-verified layout). Per instruction: 2x FLOP of 16x16x32 at the same
// operand bytes -> half the LDS reads, half the frag loads, half the MFMAs.
// GEMM1: wave w -> mt {2w,2w+1} x nt {0,1}, 1 MFMA each (K=16 exact).
// GEMM2: K=256 = 16 ksteps, acc (2mt x 2nt) x f32x16, 1-deep kk prefetch.
// GEMM3: wave w -> tile (mt=w&1, nt=w>>1), 16 ksteps.
// h LDS [64 tok][264]: row stride 528B == 4 dw-quads mod 32 banks -> b128
// reads sit at the 4-lanes-per-bank-quad floor (no swizzle needed).
// ---------------------------------------------------------------------------
__global__ __launch_bounds__(256, 4) void mlp_kernel(const float* __restrict__ x,
                                                     const float* __restrict__ b1g,
                                                     const float* __restrict__ b2g,
                                                     const short* __restrict__ ws,
                                                     float* __restrict__ y) {
  __shared__ short h1s[64 * 264];       // h2 overlays after barrier

  const int tid  = threadIdx.x;
  const int lane = tid & 63;
  const int w    = tid >> 6;            // 0..3
  const int l31  = lane & 31;
  const int hi   = lane >> 5;
  const long b   = blockIdx.x;

  const short* W2f = ws;
  const short* W3f = ws + 65536;
  const short* W1f = ws + 81920;

  const float4 xv = ((const float4*)(x + b * 1024))[tid];   // for y epilogue

  // ---- x B-frags (x^T, 16k x 32tok): tok = nt*32+l31, k = hi*8+e ----
  bf16x8 xf0, xf1;
  {
    const float4* p0 = (const float4*)(x + (b * 64 + l31) * 16 + hi * 8);
    const float4* p1 = (const float4*)(x + (b * 64 + 32 + l31) * 16 + hi * 8);
    xf0 = pack8(p0[0], p0[1]);
    xf1 = pack8(p1[0], p1[1]);
  }

  // ---- GEMM1: h1 = relu(W1 x x^T + b1) ----
#pragma unroll
  for (int i = 0; i < 2; ++i) {
    const int mt = 2 * w + i;
    const bf16x8 wa = *(const bf16x8*)(W1f + mt * 512 + lane * 8);
#pragma unroll
    for (int nt = 0; nt < 2; ++nt) {
      f32x16 c = {};
      c = MFMA32(wa, nt ? xf1 : xf0, c, 0, 0, 0);
      const int tok = nt * 32 + l31;
#pragma unroll
      for (int q = 0; q < 4; ++q) {
        const int rowb = mt * 32 + q * 8 + 4 * hi;
        const float4 bias = *(const float4*)(b1g + rowb);
        float v0 = c[q * 4 + 0] + bias.x; v0 = v0 > 0.f ? v0 : 0.f;
        float v1 = c[q * 4 + 1] + bias.y; v1 = v1 > 0.f ? v1 : 0.f;
        float v2 = c[q * 4 + 2] + bias.z; v2 = v2 > 0.f ? v2 : 0.f;
        float v3 = c[q * 4 + 3] + bias.w; v3 = v3 > 0.f ? v3 : 0.f;
        short4 st = {f2bf(v0), f2bf(v1), f2bf(v2), f2bf(v3)};
        *(short4*)(h1s + tok * 264 + rowb) = st;
      }
    }
  }
  __syncthreads();

  // ---- GEMM2: h2 = relu(W2 x h1^T + b2); 16 ksteps, 1-deep prefetch ----
  f32x16 acc2[2][2] = {};
  bf16x8 wa0, wa1, hb0, hb1, wan0, wan1, hbn0, hbn1;
  wa0 = *(const bf16x8*)(W2f + (2 * w) * 512 + lane * 8);
  wa1 = *(const bf16x8*)(W2f + (2 * w + 1) * 512 + lane * 8);
  hb0 = *(const bf16x8*)(h1s + l31 * 264 + hi * 8);
  hb1 = *(const bf16x8*)(h1s + (32 + l31) * 264 + hi * 8);
#pragma unroll
  for (int kk = 0; kk < 16; ++kk) {
    if (kk < 15) {
      const short* wb = W2f + ((kk + 1) * 8 + 2 * w) * 512 + lane * 8;
      wan0 = *(const bf16x8*)wb;
      wan1 = *(const bf16x8*)(wb + 512);
      const int co = (kk + 1) * 16 + hi * 8;
      hbn0 = *(const bf16x8*)(h1s + l31 * 264 + co);
      hbn1 = *(const bf16x8*)(h1s + (32 + l31) * 264 + co);
    }
    acc2[0][0] = MFMA32(wa0, hb0, acc2[0][0], 0, 0, 0);
    acc2[0][1] = MFMA32(wa0, hb1, acc2[0][1], 0, 0, 0);
    acc2[1][0] = MFMA32(wa1, hb0, acc2[1][0], 0, 0, 0);
    acc2[1][1] = MFMA32(wa1, hb1, acc2[1][1], 0, 0, 0);
    wa0 = wan0; wa1 = wan1; hb0 = hbn0; hb1 = hbn1;
  }
  __syncthreads();   // all h1 reads done -> overlay h2

#pragma unroll
  for (int i = 0; i < 2; ++i) {
    const int mt = 2 * w + i;
#pragma unroll
    for (int nt = 0; nt < 2; ++nt) {
      const int tok = nt * 32 + l31;
#pragma unroll
      for (int q = 0; q < 4; ++q) {
        const int rowb = mt * 32 + q * 8 + 4 * hi;
        const float4 bias = *(const float4*)(b2g + rowb);
        float v0 = acc2[i][nt][q * 4 + 0] + bias.x; v0 = v0 > 0.f ? v0 : 0.f;
        float v1 = acc2[i][nt][q * 4 + 1] + bias.y; v1 = v1 > 0.f ? v1 : 0.f;
        float v2 = acc2[i][nt][q * 4 + 2] + bias.z; v2 = v2 > 0.f ? v2 : 0.f;
        float v3 = acc2[i][nt][q * 4 + 3] + bias.w; v3 = v3 > 0.f ? v3 : 0.f;
        short4 st = {f2bf(v0), f2bf(v1), f2bf(v2), f2bf(v3)};
        *(short4*)(h1s + tok * 264 + rowb) = st;
      }
    }
  }
  __syncthreads();

  // ---- GEMM3: g = W3 x h2^T; wave w -> (mt=w&1, nt=w>>1) ----
  const int mt3 = w & 1;
  const int nt3 = w >> 1;
  const int tok3 = nt3 * 32 + l31;
  f32x16 acc3 = {};
#pragma unroll
  for (int kk = 0; kk < 16; ++kk) {
    const bf16x8 wa = *(const bf16x8*)(W3f + (kk * 2 + mt3) * 512 + lane * 8);
    const bf16x8 hb = *(const bf16x8*)(h1s + tok3 * 264 + kk * 16 + hi * 8);
    acc3 = MFMA32(wa, hb, acc3, 0, 0, 0);
  }

  // y x-part: token = tid>>2, floats (tid&3)*4..+3 (exact f32 from regs)
  *(float4*)(y + (b * 64 + (tid >> 2)) * 80 + (tid & 3) * 4) = xv;
  // y g-part: one float4 per reg-quad
#pragma unroll
  for (int q = 0; q < 4; ++q) {
    float4 st = {acc3[q * 4 + 0], acc3[q * 4 + 1], acc3[q * 4 + 2], acc3[q * 4 + 3]};
    *(float4*)(y + (b * 64 + tok3) * 80 + 16 + mt3 * 32 + q * 8 + 4 * hi) = st;
  }
}

// ---------------------------------------------------------------------------
// ypred (unchanged): y_pred[b, t, :] = y0[b] @ (K^t)^T via split-bf16 MFMA.
// ONE t per block (grid = 16 batch-chunks x 64 t), 512 thr.
// ---------------------------------------------------------------------------
__global__ __launch_bounds__(512, 4) void ypred_kernel(const short* __restrict__ ws,
                                                       const float* __restrict__ y,
                                                       float* __restrict__ yp) {
  const int tid  = threadIdx.x;
  const int lane = tid & 63;
  const int w    = tid >> 6;
  const int m16  = lane & 15;
  const int kg   = lane >> 4;
  const int bc   = blockIdx.x & 15;
  const int t    = blockIdx.x >> 4;        // 0..63
  const long b0  = (long)bc * 256;

  if (t == 0) {
    for (int i = tid; i < 5120; i += 512) {
      int r = i / 20, q = (i % 20) * 4;
      *(float4*)(yp + (b0 + r) * YROW + q) = *(const float4*)(y + (b0 + r) * YROW + q);
    }
    return;
  }

  bf16x8 ah[2][3], al[2][3];
#pragma unroll
  for (int m = 0; m < 2; ++m) {
#pragma unroll
    for (int kk = 0; kk < 3; ++kk) {
      const int k0 = kk * 32 + kg * 8;
      bf16x8 fh = {}, fl = {};
      if (k0 < 80) {
        const float4* p =
            (const float4*)(y + (b0 + (2 * w + m) * 16 + m16) * YROW + k0);
        split8(p[0], p[1], fh, fl);
      }
      ah[m][kk] = fh;
      al[m][kk] = fl;
    }
  }

  const short* kt = ws + KTAB + t * KSLOT;
  f32x4 acc[2][5];
#pragma unroll
  for (int m = 0; m < 2; ++m)
#pragma unroll
    for (int nt = 0; nt < 5; ++nt) acc[m][nt] = (f32x4){0.f, 0.f, 0.f, 0.f};

#pragma unroll
  for (int kk = 0; kk < 3; ++kk) {
#pragma unroll
    for (int nt = 0; nt < 5; ++nt) {
      const bf16x8 bh = *(const bf16x8*)(kt + ((kk * 5 + nt) * 64 + lane) * 8);
      const bf16x8 bl = *(const bf16x8*)(kt + 7680 + ((kk * 5 + nt) * 64 + lane) * 8);
#pragma unroll
      for (int m = 0; m < 2; ++m) {
        acc[m][nt] = MFMA(ah[m][kk], bh, acc[m][nt], 0, 0, 0);
        acc[m][nt] = MFMA(al[m][kk], bh, acc[m][nt], 0, 0, 0);
        acc[m][nt] = MFMA(ah[m][kk], bl, acc[m][nt], 0, 0, 0);
      }
    }
  }
#pragma unroll
  for (int m = 0; m < 2; ++m)
#pragma unroll
    for (int nt = 0; nt < 5; ++nt)
#pragma unroll
      for (int r = 0; r < 4; ++r)
        yp[(b0 + (2 * w + m) * 16 + kg * 4 + r) * YROW + (long)t * 80 + nt * 16 + m16] =
            acc[m][nt][r];
}

extern "C" void kernel_launch(void* const* d_in, const int* in_sizes, int n_in,
                              void* d_out, int out_size, void* d_ws, size_t ws_size,
                              hipStream_t stream) {
  const float* x  = (const float*)d_in[0];
  const float* W1 = (const float*)d_in[1];
  const float* b1 = (const float*)d_in[2];
  const float* W2 = (const float*)d_in[3];
  const float* b2 = (const float*)d_in[4];
  const float* W3 = (const float*)d_in[5];
  const float* Kg = (const float*)d_in[6];
  float* y  = (float*)d_out;
  float* yp = y + (long)NB * YROW;
  short* ws = (short*)d_ws;

  prep_kernel<<<256, 256, 0, stream>>>(W1, W2, W3, ws);
  kpow_kernel<<<63, 512, 5 * FIMG_B, stream>>>(Kg, ws);
  mlp_kernel<<<NB, 256, 0, stream>>>(x, b1, b2, ws, y);
  ypred_kernel<<<16 * 64, 512, 0, stream>>>(ws, y, yp);
}

// Round 10
// 127.079 us; speedup vs baseline: 1.0191x; 1.0191x over previous
//
#include <hip/hip_runtime.h>
#include <hip/hip_bf16.h>

// Problem constants (hardcoded from setup_inputs; n_shifts == T == 64)
#define NB   4096
#define NT   64
#define NDIM 16
#define NH1  256
#define NH2  256
#define NLAT 64
#define NKD  80
#define YROW (NT * NKD)      // 5120 floats per batch row of y / y_pred
#define KTAB 98304           // short-offset of K-power fragment table in ws
#define KSLOT 15360          // shorts per t-slot (7680 hi + 7680 lo)
#define Y0OFF 1081344        // short-offset of y0 table (4096 x 80 f32)

// kpow frag-image geometry: hi at [row][0..79], lo at [row][96..175]
#define FROW 184
#define FIMG_B (80 * FROW * 2)   // 29440 bytes per image

typedef __attribute__((ext_vector_type(8))) short bf16x8;
typedef __attribute__((ext_vector_type(4))) float f32x4;

#define MFMA __builtin_amdgcn_mfma_f32_16x16x32_bf16

static __device__ __forceinline__ short f2bf(float f) {
  union { float f; unsigned u; } v; v.f = f;
  unsigned r = v.u + 0x7fffu + ((v.u >> 16) & 1u);   // RNE
  return (short)(r >> 16);
}
static __device__ __forceinline__ float bf2f(short h) {
  union { unsigned u; float f; } v; v.u = ((unsigned)(unsigned short)h) << 16;
  return v.f;
}
static __device__ __forceinline__ bf16x8 pack8(float4 a, float4 b) {
  bf16x8 r;
  r[0] = f2bf(a.x); r[1] = f2bf(a.y); r[2] = f2bf(a.z); r[3] = f2bf(a.w);
  r[4] = f2bf(b.x); r[5] = f2bf(b.y); r[6] = f2bf(b.z); r[7] = f2bf(b.w);
  return r;
}
static __device__ __forceinline__ void split8(float4 v0, float4 v1, bf16x8& h, bf16x8& l) {
  h = pack8(v0, v1);
  float4 r0, r1;
  r0.x = v0.x - bf2f(h[0]); r0.y = v0.y - bf2f(h[1]);
  r0.z = v0.z - bf2f(h[2]); r0.w = v0.w - bf2f(h[3]);
  r1.x = v1.x - bf2f(h[4]); r1.y = v1.y - bf2f(h[5]);
  r1.z = v1.z - bf2f(h[6]); r1.w = v1.w - bf2f(h[7]);
  l = pack8(r0, r1);
}

// ---------------------------------------------------------------------------
// Prep (round-8 version): MFMA fragment order (bf16) for 16x16x32.
// Fragment: lane l holds W[g][k] with g = l&15, k = 8*(l>>4)+e.
// ws (shorts): [0) W2f 65536 | [65536) W3f 16384 | [81920) W1f 8192
// ---------------------------------------------------------------------------
__global__ __launch_bounds__(256) void prep_kernel(const float* __restrict__ W1,
                                                   const float* __restrict__ W2,
                                                   const float* __restrict__ W3,
                                                   short* __restrict__ ws) {
  int i = blockIdx.x * 256 + threadIdx.x;   // 0..65535
  {
    int e = i & 7, l = (i >> 3) & 63, nt = (i >> 9) & 15, kk = i >> 13;
    int g = nt * 16 + (l & 15);
    int h = kk * 32 + (l >> 4) * 8 + e;
    ws[i] = f2bf(W2[g * NH1 + h]);
  }
  if (i < 16384) {
    int e = i & 7, l = (i >> 3) & 63, nt = (i >> 9) & 3, kk = i >> 11;
    int g = nt * 16 + (l & 15);
    int h = kk * 32 + (l >> 4) * 8 + e;
    ws[65536 + i] = f2bf(W3[g * NH2 + h]);
  }
  if (i < 8192) {
    int e = i & 7, l = (i >> 3) & 63, nt = i >> 9;
    int g = nt * 16 + (l & 15);
    int k = (l >> 4) * 8 + e;
    ws[81920 + i] = (k < NDIM) ? f2bf(W1[g * NDIM + k]) : (short)0;
  }
}

// ---------------------------------------------------------------------------
// kpow v3 (unchanged, proven ~5 us): binary exponentiation with the running
// power kept as PRE-SPLIT hi/lo bf16 frag images in both orientations.
// ---------------------------------------------------------------------------
__global__ void kpow_kernel(const float* __restrict__ Kg, short* __restrict__ ws) {
  extern __shared__ char smem[];
  short* kA   = (short*)smem;
  short* curA = (short*)(smem + FIMG_B);
  short* curB = (short*)(smem + 2 * FIMG_B);
  short* nxtA = (short*)(smem + 3 * FIMG_B);
  short* nxtB = (short*)(smem + 4 * FIMG_B);

  const int tid  = threadIdx.x;
  const int lane = tid & 63;
  const int w    = tid >> 6;
  const int l15  = lane & 15;
  const int kg   = lane >> 4;
  const int t    = blockIdx.x + 1;          // 1..63

  for (int i = tid; i < 6400; i += 512) {
    float v = Kg[i];
    int r = i / 80, c = i - r * 80;
    short hi = f2bf(v);
    short lo = f2bf(v - bf2f(hi));
    kA[r * FROW + c] = hi;        kA[r * FROW + 96 + c] = lo;
    curA[r * FROW + c] = hi;      curA[r * FROW + 96 + c] = lo;
    curB[c * FROW + r] = hi;      curB[c * FROW + 96 + r] = lo;
  }
  __syncthreads();

  auto mm = [&](const short* Ai, const short* Bi, short* DA, short* DB) {
    for (int id = w; id < 25; id += 8) {
      const int mt = id / 5, nt = id % 5;
      f32x4 acc = {0.f, 0.f, 0.f, 0.f};
#pragma unroll
      for (int kk = 0; kk < 3; ++kk) {
        const int k0 = kk * 32 + kg * 8;
        bf16x8 ah = {}, al = {}, bh = {}, bl = {};
        if (k0 < 80) {
          const short* ap = Ai + (mt * 16 + l15) * FROW + k0;
          const short* bp = Bi + (nt * 16 + l15) * FROW + k0;
          ah = *(const bf16x8*)ap;  al = *(const bf16x8*)(ap + 96);
          bh = *(const bf16x8*)bp;  bl = *(const bf16x8*)(bp + 96);
        }
        acc = MFMA(ah, bh, acc, 0, 0, 0);
        acc = MFMA(al, bh, acc, 0, 0, 0);
        acc = MFMA(ah, bl, acc, 0, 0, 0);
      }
      const int n = nt * 16 + l15;
      const int rowb = mt * 16 + kg * 4;
      short4 hs, ls;
#pragma unroll
      for (int r = 0; r < 4; ++r) {
        float v = acc[r];
        short hi = f2bf(v);
        short lo = f2bf(v - bf2f(hi));
        DA[(rowb + r) * FROW + n] = hi;
        DA[(rowb + r) * FROW + 96 + n] = lo;
        ((short*)&hs)[r] = hi;
        ((short*)&ls)[r] = lo;
      }
      *(short4*)(DB + n * FROW + rowb) = hs;
      *(short4*)(DB + n * FROW + 96 + rowb) = ls;
    }
    __syncthreads();
  };

  const int h = 31 - __clz(t);
  for (int bit = h - 1; bit >= 0; --bit) {
    mm(curA, curB, nxtA, nxtB);                               // square
    { short* p;
      p = curA; curA = nxtA; nxtA = p;
      p = curB; curB = nxtB; nxtB = p; }
    if ((t >> bit) & 1) {
      mm(kA, curB, nxtA, nxtB);                               // K * cur
      { short* p;
        p = curA; curA = nxtA; nxtA = p;
        p = curB; curB = nxtB; nxtB = p; }
    }
  }

  short* kt = ws + KTAB + t * KSLOT;
  for (int s = tid; s < 960; s += 512) {
    int f = s >> 6, ln = s & 63;            // f = kk*5 + nt
    int kk = f / 5, nt = f % 5;
    int k0 = kk * 32 + (ln >> 4) * 8;
    int n  = nt * 16 + (ln & 15);
    bf16x8 h8 = {}, l8 = {};
    if (k0 < 80) {
      const short* ap = curA + n * FROW + k0;
      h8 = *(const bf16x8*)ap;
      l8 = *(const bf16x8*)(ap + 96);
    }
    *(bf16x8*)(kt + f * 512 + ln * 8) = h8;
    *(bf16x8*)(kt + 7680 + f * 512 + ln * 8) = l8;
  }
}

// ---------------------------------------------------------------------------
// MLP body (round-8 proven version, 16x16x32, swapped operands, 4 waves,
// one batch row of 64 tokens). Parameterized over token gather so the same
// body serves the full MLP (contiguous 64 tokens of row b) and mlp0
// (token 0 of 64 consecutive batch rows; XSTRIDE = floats between tokens).
// ---------------------------------------------------------------------------
template <int XSTRIDE, int OROW>
static __device__ __forceinline__ void mlp_body(long b, const float* __restrict__ x,
                                                const float* __restrict__ b1g,
                                                const float* __restrict__ b2g,
                                                const short* __restrict__ ws,
                                                float* __restrict__ yo, short* h1s,
                                                int tid) {
  const int lane = tid & 63;
  const int w    = tid >> 6;            // 0..3
  const int l15  = lane & 15;
  const int kg   = lane >> 4;

  const short* W2f = ws;
  const short* W3f = ws + 65536;
  const short* W1f = ws + 81920;

  const float4 xv =
      *(const float4*)(x + (b * 64 + (tid >> 2)) * XSTRIDE + (tid & 3) * 4);

  // ---- x B-frags (x^T): lane holds x[tok][k0..k0+7], tok = col ----
  bf16x8 xf[4];
#pragma unroll
  for (int j = 0; j < 4; ++j) {
    const int tok = j * 16 + l15;
    bf16x8 f = {};
    if (kg < 2) {
      const float4* p = (const float4*)(x + (b * 64 + tok) * XSTRIDE + kg * 8);
      f = pack8(p[0], p[1]);
    }
    xf[j] = f;
  }

  // ---- GEMM1: D = W1 x x^T -> h1[tok][h] via packed b64 stores ----
#pragma unroll
  for (int i = 0; i < 4; ++i) {
    const int mt = w * 4 + i;
    const bf16x8 wa = *(const bf16x8*)(W1f + (mt * 64 + lane) * 8);
    const float4 bias = *(const float4*)(b1g + mt * 16 + kg * 4);
#pragma unroll
    for (int j = 0; j < 4; ++j) {
      f32x4 c = {0.f, 0.f, 0.f, 0.f};
      c = MFMA(wa, xf[j], c, 0, 0, 0);
      const int tok = j * 16 + l15;
      float v0 = c[0] + bias.x; v0 = v0 > 0.f ? v0 : 0.f;
      float v1 = c[1] + bias.y; v1 = v1 > 0.f ? v1 : 0.f;
      float v2 = c[2] + bias.z; v2 = v2 > 0.f ? v2 : 0.f;
      float v3 = c[3] + bias.w; v3 = v3 > 0.f ? v3 : 0.f;
      short4 st = {f2bf(v0), f2bf(v1), f2bf(v2), f2bf(v3)};
      *(short4*)(h1s + tok * 264 + mt * 16 + kg * 4) = st;
    }
  }
  __syncthreads();

  // ---- GEMM2: D = W2 x h1^T; K=256; acc 4mt x 4nt ----
  f32x4 acc2[4][4];
#pragma unroll
  for (int i = 0; i < 4; ++i)
#pragma unroll
    for (int j = 0; j < 4; ++j) acc2[i][j] = (f32x4){0.f, 0.f, 0.f, 0.f};

#pragma unroll 2
  for (int kk = 0; kk < 8; ++kk) {
    bf16x8 wa[4], hb[4];
#pragma unroll
    for (int i = 0; i < 4; ++i)
      wa[i] = *(const bf16x8*)(W2f + ((kk * 16 + w * 4 + i) * 64 + lane) * 8);
#pragma unroll
    for (int j = 0; j < 4; ++j)
      hb[j] = *(const bf16x8*)(h1s + (j * 16 + l15) * 264 + kk * 32 + kg * 8);
#pragma unroll
    for (int i = 0; i < 4; ++i)
#pragma unroll
      for (int j = 0; j < 4; ++j)
        acc2[i][j] = MFMA(wa[i], hb[j], acc2[i][j], 0, 0, 0);
  }
  __syncthreads();   // all h1 reads done -> overlay h2

#pragma unroll
  for (int i = 0; i < 4; ++i) {
    const int mt = w * 4 + i;
    const float4 bias = *(const float4*)(b2g + mt * 16 + kg * 4);
#pragma unroll
    for (int j = 0; j < 4; ++j) {
      const int tok = j * 16 + l15;
      float v0 = acc2[i][j][0] + bias.x; v0 = v0 > 0.f ? v0 : 0.f;
      float v1 = acc2[i][j][1] + bias.y; v1 = v1 > 0.f ? v1 : 0.f;
      float v2 = acc2[i][j][2] + bias.z; v2 = v2 > 0.f ? v2 : 0.f;
      float v3 = acc2[i][j][3] + bias.w; v3 = v3 > 0.f ? v3 : 0.f;
      short4 st = {f2bf(v0), f2bf(v1), f2bf(v2), f2bf(v3)};
      *(short4*)(h1s + tok * 264 + mt * 16 + kg * 4) = st;
    }
  }
  __syncthreads();

  // ---- GEMM3: D = W3 x h2^T; y stored straight from registers ----
  f32x4 acc3[4];
#pragma unroll
  for (int j = 0; j < 4; ++j) acc3[j] = (f32x4){0.f, 0.f, 0.f, 0.f};
#pragma unroll 2
  for (int kk = 0; kk < 8; ++kk) {
    const bf16x8 wa = *(const bf16x8*)(W3f + ((kk * 4 + w) * 64 + lane) * 8);
#pragma unroll
    for (int j = 0; j < 4; ++j) {
      const bf16x8 hb =
          *(const bf16x8*)(h1s + (j * 16 + l15) * 264 + kk * 32 + kg * 8);
      acc3[j] = MFMA(wa, hb, acc3[j], 0, 0, 0);
    }
  }

  // y x-part (exact f32 from regs) + g-part (one float4 per tile)
  *(float4*)(yo + (b * 64 + (tid >> 2)) * OROW + (tid & 3) * 4) = xv;
#pragma unroll
  for (int j = 0; j < 4; ++j) {
    const int tok = j * 16 + l15;
    *(float4*)(yo + (b * 64 + tok) * OROW + 16 + w * 16 + kg * 4) =
        *(float4*)&acc3[j];
  }
}

// ---------------------------------------------------------------------------
// mlp0: token-0-only MLP for all 4096 batch rows (64 blocks x 64 rows).
// Token gather stride = 1024 floats (row pitch of x); writes 80-float y0
// rows into ws at Y0OFF. ~2 us; enables ypred to run without the full MLP.
// ---------------------------------------------------------------------------
__global__ __launch_bounds__(256, 4) void mlp0_kernel(const float* __restrict__ x,
                                                      const float* __restrict__ b1g,
                                                      const float* __restrict__ b2g,
                                                      short* __restrict__ ws) {
  __shared__ short h1s[64 * 264];
  float* y0t = (float*)(ws + Y0OFF);
  mlp_body<1024, 80>((long)blockIdx.x, x, b1g, b2g, ws, y0t, h1s, threadIdx.x);
}

// ---------------------------------------------------------------------------
// ypred body (256-thr): block = (bc 128 batch rows, one t). Wave w owns
// M-tiles {2w, 2w+1} of 8. A hi/lo frags from the y0 table; B-frags from the
// precomputed hi/lo K^t table. t=0 blocks copy y0 -> yp.
// ---------------------------------------------------------------------------
static __device__ __forceinline__ void ypred_body(int g, const short* __restrict__ ws,
                                                  float* __restrict__ yp, int tid) {
  const int lane = tid & 63;
  const int w    = tid >> 6;           // 0..3
  const int m16  = lane & 15;
  const int kg   = lane >> 4;
  const int bc   = g & 31;
  const int t    = g >> 5;             // 0..63
  const long b0  = (long)bc * 128;
  const float* y0t = (const float*)(ws + Y0OFF);

  if (t == 0) {
    for (int i = tid; i < 2560; i += 256) {
      int r = i / 20, q = (i % 20) * 4;
      *(float4*)(yp + (b0 + r) * YROW + q) = *(const float4*)(y0t + (b0 + r) * 80 + q);
    }
    return;
  }

  bf16x8 ah[2][3], al[2][3];
#pragma unroll
  for (int m = 0; m < 2; ++m) {
#pragma unroll
    for (int kk = 0; kk < 3; ++kk) {
      const int k0 = kk * 32 + kg * 8;
      bf16x8 fh = {}, fl = {};
      if (k0 < 80) {
        const float4* p =
            (const float4*)(y0t + (b0 + (2 * w + m) * 16 + m16) * 80 + k0);
        split8(p[0], p[1], fh, fl);
      }
      ah[m][kk] = fh;
      al[m][kk] = fl;
    }
  }

  const short* kt = ws + KTAB + t * KSLOT;
  f32x4 acc[2][5];
#pragma unroll
  for (int m = 0; m < 2; ++m)
#pragma unroll
    for (int nt = 0; nt < 5; ++nt) acc[m][nt] = (f32x4){0.f, 0.f, 0.f, 0.f};

#pragma unroll
  for (int kk = 0; kk < 3; ++kk) {
#pragma unroll
    for (int nt = 0; nt < 5; ++nt) {
      const bf16x8 bh = *(const bf16x8*)(kt + ((kk * 5 + nt) * 64 + lane) * 8);
      const bf16x8 bl = *(const bf16x8*)(kt + 7680 + ((kk * 5 + nt) * 64 + lane) * 8);
#pragma unroll
      for (int m = 0; m < 2; ++m) {
        acc[m][nt] = MFMA(ah[m][kk], bh, acc[m][nt], 0, 0, 0);
        acc[m][nt] = MFMA(al[m][kk], bh, acc[m][nt], 0, 0, 0);
        acc[m][nt] = MFMA(ah[m][kk], bl, acc[m][nt], 0, 0, 0);
      }
    }
  }
#pragma unroll
  for (int m = 0; m < 2; ++m)
#pragma unroll
    for (int nt = 0; nt < 5; ++nt)
#pragma unroll
      for (int r = 0; r < 4; ++r)
        yp[(b0 + (2 * w + m) * 16 + kg * 4 + r) * YROW + (long)t * 80 + nt * 16 + m16] =
            acc[m][nt][r];
}

// ---------------------------------------------------------------------------
// Fused kernel: 6144 blocks. bid%3==2 -> ypred block (2048: write-BW bound),
// else -> mlp block (4096: latency bound). 1:3 interleave co-resides the two
// on each CU so ypred's HBM writes hide under mlp's stalls.
// ---------------------------------------------------------------------------
__global__ __launch_bounds__(256, 4) void fused_kernel(const float* __restrict__ x,
                                                       const float* __restrict__ b1g,
                                                       const float* __restrict__ b2g,
                                                       const short* __restrict__ ws,
                                                       float* __restrict__ y,
                                                       float* __restrict__ yp) {
  extern __shared__ char smem[];
  const int bid = blockIdx.x;
  const int g = bid / 3;
  const int r = bid - 3 * g;
  if (r == 2) {
    ypred_body(g, ws, yp, threadIdx.x);
  } else {
    mlp_body<16, 80>((long)(g * 2 + r), x, b1g, b2g, ws, y, (short*)smem,
                     threadIdx.x);
  }
}

extern "C" void kernel_launch(void* const* d_in, const int* in_sizes, int n_in,
                              void* d_out, int out_size, void* d_ws, size_t ws_size,
                              hipStream_t stream) {
  const float* x  = (const float*)d_in[0];
  const float* W1 = (const float*)d_in[1];
  const float* b1 = (const float*)d_in[2];
  const float* W2 = (const float*)d_in[3];
  const float* b2 = (const float*)d_in[4];
  const float* W3 = (const float*)d_in[5];
  const float* Kg = (const float*)d_in[6];
  float* y  = (float*)d_out;
  float* yp = y + (long)NB * YROW;
  short* ws = (short*)d_ws;

  prep_kernel<<<256, 256, 0, stream>>>(W1, W2, W3, ws);
  kpow_kernel<<<63, 512, 5 * FIMG_B, stream>>>(Kg, ws);
  mlp0_kernel<<<64, 256, 0, stream>>>(x, b1, b2, ws);
  fused_kernel<<<6144, 256, 64 * 264 * 2, stream>>>(x, b1, b2, ws, y, yp);
}

// Round 11
// 116.770 us; speedup vs baseline: 1.1090x; 1.0883x over previous
//
#include <hip/hip_runtime.h>
#include <hip/hip_bf16.h>

// Problem constants (hardcoded from setup_inputs; n_shifts == T == 64)
#define NB   4096
#define NT   64
#define NDIM 16
#define NH1  256
#define NH2  256
#define NLAT 64
#define NKD  80
#define YROW (NT * NKD)      // 5120 floats per batch row of y / y_pred
#define KTAB 98304           // short-offset of K-power fragment table in ws
#define KSLOT 15360          // shorts per t-slot (7680 hi + 7680 lo)
#define Y0F   1081344        // short-offset of y0 A-frag table
#define HPLANE 393216        // shorts per plane: 256 mtiles x 3 kk x 64 lane x 8 e

// kpow frag-image geometry: hi at [row][0..79], lo at [row][96..175]
#define FROW 184
#define FIMG_B (80 * FROW * 2)   // 29440 bytes per image

typedef __attribute__((ext_vector_type(8))) short bf16x8;
typedef __attribute__((ext_vector_type(4))) float f32x4;

#define MFMA __builtin_amdgcn_mfma_f32_16x16x32_bf16

static __device__ __forceinline__ short f2bf(float f) {
  __hip_bfloat16 b = __float2bfloat16(f);      // native RNE cast (m240)
  return __builtin_bit_cast(short, b);
}
static __device__ __forceinline__ float bf2f(short h) {
  union { unsigned u; float f; } v; v.u = ((unsigned)(unsigned short)h) << 16;
  return v.f;
}
static __device__ __forceinline__ bf16x8 pack8(float4 a, float4 b) {
  bf16x8 r;
  r[0] = f2bf(a.x); r[1] = f2bf(a.y); r[2] = f2bf(a.z); r[3] = f2bf(a.w);
  r[4] = f2bf(b.x); r[5] = f2bf(b.y); r[6] = f2bf(b.z); r[7] = f2bf(b.w);
  return r;
}

// ---------------------------------------------------------------------------
// Prep: MFMA fragment order (bf16) for 16x16x32.
// Fragment: lane l holds W[g][k] with g = l&15, k = 8*(l>>4)+e.
// ws (shorts): [0) W2f 65536 | [65536) W3f 16384 | [81920) W1f 8192
// ---------------------------------------------------------------------------
__global__ __launch_bounds__(256) void prep_kernel(const float* __restrict__ W1,
                                                   const float* __restrict__ W2,
                                                   const float* __restrict__ W3,
                                                   short* __restrict__ ws) {
  int i = blockIdx.x * 256 + threadIdx.x;   // 0..65535
  {
    int e = i & 7, l = (i >> 3) & 63, nt = (i >> 9) & 15, kk = i >> 13;
    int g = nt * 16 + (l & 15);
    int h = kk * 32 + (l >> 4) * 8 + e;
    ws[i] = f2bf(W2[g * NH1 + h]);
  }
  if (i < 16384) {
    int e = i & 7, l = (i >> 3) & 63, nt = (i >> 9) & 3, kk = i >> 11;
    int g = nt * 16 + (l & 15);
    int h = kk * 32 + (l >> 4) * 8 + e;
    ws[65536 + i] = f2bf(W3[g * NH2 + h]);
  }
  if (i < 8192) {
    int e = i & 7, l = (i >> 3) & 63, nt = i >> 9;
    int g = nt * 16 + (l & 15);
    int k = (l >> 4) * 8 + e;
    ws[81920 + i] = (k < NDIM) ? f2bf(W1[g * NDIM + k]) : (short)0;
  }
}

// ---------------------------------------------------------------------------
// MLP body (round-8 proven, 16x16x32, swapped operands, 4 waves, 64 tokens).
// MODE 0: write y rows (80 floats/token). MODE 1 (mlp0): write the y0 hi/lo
// A-fragment table at ws[Y0F] instead (plane layout [gmt][kk][lane][e]).
// ---------------------------------------------------------------------------
template <int XSTRIDE, int MODE>
static __device__ __forceinline__ void mlp_body(long b, const float* __restrict__ x,
                                                const float* __restrict__ b1g,
                                                const float* __restrict__ b2g,
                                                const short* __restrict__ ws,
                                                float* __restrict__ yo,
                                                short* __restrict__ y0f,
                                                short* h1s, int tid) {
  const int lane = tid & 63;
  const int w    = tid >> 6;            // 0..3
  const int l15  = lane & 15;
  const int kg   = lane >> 4;

  const short* W2f = ws;
  const short* W3f = ws + 65536;
  const short* W1f = ws + 81920;

  const float4 xv =
      *(const float4*)(x + (b * 64 + (tid >> 2)) * XSTRIDE + (tid & 3) * 4);

  // ---- x B-frags (x^T): lane holds x[tok][k0..k0+7], tok = col ----
  bf16x8 xf[4];
#pragma unroll
  for (int j = 0; j < 4; ++j) {
    const int tok = j * 16 + l15;
    bf16x8 f = {};
    if (kg < 2) {
      const float4* p = (const float4*)(x + (b * 64 + tok) * XSTRIDE + kg * 8);
      f = pack8(p[0], p[1]);
    }
    xf[j] = f;
  }

  // ---- GEMM1: D = W1 x x^T -> h1[tok][h] via packed b64 stores ----
#pragma unroll
  for (int i = 0; i < 4; ++i) {
    const int mt = w * 4 + i;
    const bf16x8 wa = *(const bf16x8*)(W1f + (mt * 64 + lane) * 8);
    const float4 bias = *(const float4*)(b1g + mt * 16 + kg * 4);
#pragma unroll
    for (int j = 0; j < 4; ++j) {
      f32x4 c = {0.f, 0.f, 0.f, 0.f};
      c = MFMA(wa, xf[j], c, 0, 0, 0);
      const int tok = j * 16 + l15;
      float v0 = c[0] + bias.x; v0 = v0 > 0.f ? v0 : 0.f;
      float v1 = c[1] + bias.y; v1 = v1 > 0.f ? v1 : 0.f;
      float v2 = c[2] + bias.z; v2 = v2 > 0.f ? v2 : 0.f;
      float v3 = c[3] + bias.w; v3 = v3 > 0.f ? v3 : 0.f;
      short4 st = {f2bf(v0), f2bf(v1), f2bf(v2), f2bf(v3)};
      *(short4*)(h1s + tok * 264 + mt * 16 + kg * 4) = st;
    }
  }
  __syncthreads();

  // ---- GEMM2: D = W2 x h1^T; K=256; acc 4mt x 4nt ----
  f32x4 acc2[4][4];
#pragma unroll
  for (int i = 0; i < 4; ++i)
#pragma unroll
    for (int j = 0; j < 4; ++j) acc2[i][j] = (f32x4){0.f, 0.f, 0.f, 0.f};

#pragma unroll 2
  for (int kk = 0; kk < 8; ++kk) {
    bf16x8 wa[4], hb[4];
#pragma unroll
    for (int i = 0; i < 4; ++i)
      wa[i] = *(const bf16x8*)(W2f + ((kk * 16 + w * 4 + i) * 64 + lane) * 8);
#pragma unroll
    for (int j = 0; j < 4; ++j)
      hb[j] = *(const bf16x8*)(h1s + (j * 16 + l15) * 264 + kk * 32 + kg * 8);
#pragma unroll
    for (int i = 0; i < 4; ++i)
#pragma unroll
      for (int j = 0; j < 4; ++j)
        acc2[i][j] = MFMA(wa[i], hb[j], acc2[i][j], 0, 0, 0);
  }
  __syncthreads();   // all h1 reads done -> overlay h2

#pragma unroll
  for (int i = 0; i < 4; ++i) {
    const int mt = w * 4 + i;
    const float4 bias = *(const float4*)(b2g + mt * 16 + kg * 4);
#pragma unroll
    for (int j = 0; j < 4; ++j) {
      const int tok = j * 16 + l15;
      float v0 = acc2[i][j][0] + bias.x; v0 = v0 > 0.f ? v0 : 0.f;
      float v1 = acc2[i][j][1] + bias.y; v1 = v1 > 0.f ? v1 : 0.f;
      float v2 = acc2[i][j][2] + bias.z; v2 = v2 > 0.f ? v2 : 0.f;
      float v3 = acc2[i][j][3] + bias.w; v3 = v3 > 0.f ? v3 : 0.f;
      short4 st = {f2bf(v0), f2bf(v1), f2bf(v2), f2bf(v3)};
      *(short4*)(h1s + tok * 264 + mt * 16 + kg * 4) = st;
    }
  }
  __syncthreads();

  // ---- GEMM3: D = W3 x h2^T ----
  f32x4 acc3[4];
#pragma unroll
  for (int j = 0; j < 4; ++j) acc3[j] = (f32x4){0.f, 0.f, 0.f, 0.f};
#pragma unroll 2
  for (int kk = 0; kk < 8; ++kk) {
    const bf16x8 wa = *(const bf16x8*)(W3f + ((kk * 4 + w) * 64 + lane) * 8);
#pragma unroll
    for (int j = 0; j < 4; ++j) {
      const bf16x8 hb =
          *(const bf16x8*)(h1s + (j * 16 + l15) * 264 + kk * 32 + kg * 8);
      acc3[j] = MFMA(wa, hb, acc3[j], 0, 0, 0);
    }
  }

  if (MODE == 0) {
    // y x-part (exact f32 from regs) + g-part (one float4 per tile)
    *(float4*)(yo + (b * 64 + (tid >> 2)) * 80 + (tid & 3) * 4) = xv;
#pragma unroll
    for (int j = 0; j < 4; ++j) {
      const int tok = j * 16 + l15;
      *(float4*)(yo + (b * 64 + tok) * 80 + 16 + w * 16 + kg * 4) =
          *(float4*)&acc3[j];
    }
  } else {
    // ---- y0 hi/lo A-frag table epilogue ----
    // x part: token t0 = tid>>2, cols c0x = (tid&3)*4 (kk = 0)
    {
      const int t0 = tid >> 2;
      const int gmt = (int)b * 4 + (t0 >> 4);
      const int c0x = (tid & 3) * 4;
      const int lanef = (c0x >> 3) * 16 + (t0 & 15);
      short h0 = f2bf(xv.x), h1 = f2bf(xv.y), h2 = f2bf(xv.z), h3 = f2bf(xv.w);
      short4 hs = {h0, h1, h2, h3};
      short4 ls = {f2bf(xv.x - bf2f(h0)), f2bf(xv.y - bf2f(h1)),
                   f2bf(xv.z - bf2f(h2)), f2bf(xv.w - bf2f(h3))};
      const int idx = ((gmt * 3 + 0) * 64 + lanef) * 8 + (c0x & 7);
      *(short4*)(y0f + idx) = hs;
      *(short4*)(y0f + HPLANE + idx) = ls;
    }
    // g part: cols c0 = 16 + w*16 + kg*4 of token j*16+l15
    const int c0 = 16 + w * 16 + kg * 4;
    const int kkf = c0 >> 5;
    const int lanef = ((c0 & 31) >> 3) * 16 + l15;
#pragma unroll
    for (int j = 0; j < 4; ++j) {
      const int gmt = (int)b * 4 + j;
      short h0 = f2bf(acc3[j][0]), h1 = f2bf(acc3[j][1]);
      short h2 = f2bf(acc3[j][2]), h3 = f2bf(acc3[j][3]);
      short4 hs = {h0, h1, h2, h3};
      short4 ls = {f2bf(acc3[j][0] - bf2f(h0)), f2bf(acc3[j][1] - bf2f(h1)),
                   f2bf(acc3[j][2] - bf2f(h2)), f2bf(acc3[j][3] - bf2f(h3))};
      const int idx = ((gmt * 3 + kkf) * 64 + lanef) * 8 + (c0 & 7);
      *(short4*)(y0f + idx) = hs;
      *(short4*)(y0f + HPLANE + idx) = ls;
    }
    // zero-fill k in [80,96): kk=2, lanes 32..63 (ws is poisoned, not zeroed)
    {
      const int plane = tid & 1;
      const int lz = 32 + ((tid >> 1) & 31);
      const int gmt = (int)b * 4 + (tid >> 6);
      bf16x8 z = {};
      *(bf16x8*)(y0f + plane * HPLANE + ((gmt * 3 + 2) * 64 + lz) * 8) = z;
    }
  }
}

// ---------------------------------------------------------------------------
// kpow+mlp0 fused launch (127 blocks, 256 thr):
//   bid 0..62  -> kpow: K^(bid+1) via binary exponentiation, pre-split hi/lo
//                 frag images in LDS (proven round-7 structure, 4-wave mm).
//   bid 63..126-> mlp0: token-0 MLP for 64 batch rows, emitting the y0
//                 hi/lo A-frag table. Concurrent with kpow (127 < 256 CUs).
// ---------------------------------------------------------------------------
__global__ __launch_bounds__(256, 4) void kpow_mlp0_kernel(const float* __restrict__ Kg,
                                                           const float* __restrict__ x,
                                                           const float* __restrict__ b1g,
                                                           const float* __restrict__ b2g,
                                                           short* __restrict__ ws) {
  extern __shared__ char smem[];
  const int tid = threadIdx.x;

  if (blockIdx.x >= 63) {
    mlp_body<1024, 1>((long)(blockIdx.x - 63), x, b1g, b2g, ws, nullptr,
                      ws + Y0F, (short*)smem, tid);
    return;
  }

  short* kA   = (short*)smem;
  short* curA = (short*)(smem + FIMG_B);
  short* curB = (short*)(smem + 2 * FIMG_B);
  short* nxtA = (short*)(smem + 3 * FIMG_B);
  short* nxtB = (short*)(smem + 4 * FIMG_B);

  const int lane = tid & 63;
  const int w    = tid >> 6;            // 0..3
  const int l15  = lane & 15;
  const int kg   = lane >> 4;
  const int t    = blockIdx.x + 1;      // 1..63

  for (int i = tid; i < 6400; i += 256) {
    float v = Kg[i];
    int r = i / 80, c = i - r * 80;
    short hi = f2bf(v);
    short lo = f2bf(v - bf2f(hi));
    kA[r * FROW + c] = hi;        kA[r * FROW + 96 + c] = lo;
    curA[r * FROW + c] = hi;      curA[r * FROW + 96 + c] = lo;
    curB[c * FROW + r] = hi;      curB[c * FROW + 96 + r] = lo;
  }
  __syncthreads();

  auto mm = [&](const short* Ai, const short* Bi, short* DA, short* DB) {
    for (int id = w; id < 25; id += 4) {
      const int mt = id / 5, nt = id % 5;
      f32x4 acc = {0.f, 0.f, 0.f, 0.f};
#pragma unroll
      for (int kk = 0; kk < 3; ++kk) {
        const int k0 = kk * 32 + kg * 8;
        bf16x8 ah = {}, al = {}, bh = {}, bl = {};
        if (k0 < 80) {
          const short* ap = Ai + (mt * 16 + l15) * FROW + k0;
          const short* bp = Bi + (nt * 16 + l15) * FROW + k0;
          ah = *(const bf16x8*)ap;  al = *(const bf16x8*)(ap + 96);
          bh = *(const bf16x8*)bp;  bl = *(const bf16x8*)(bp + 96);
        }
        acc = MFMA(ah, bh, acc, 0, 0, 0);
        acc = MFMA(al, bh, acc, 0, 0, 0);
        acc = MFMA(ah, bl, acc, 0, 0, 0);
      }
      const int n = nt * 16 + l15;
      const int rowb = mt * 16 + kg * 4;
      short4 hs, ls;
#pragma unroll
      for (int r = 0; r < 4; ++r) {
        float v = acc[r];
        short hi = f2bf(v);
        short lo = f2bf(v - bf2f(hi));
        DA[(rowb + r) * FROW + n] = hi;
        DA[(rowb + r) * FROW + 96 + n] = lo;
        ((short*)&hs)[r] = hi;
        ((short*)&ls)[r] = lo;
      }
      *(short4*)(DB + n * FROW + rowb) = hs;
      *(short4*)(DB + n * FROW + 96 + rowb) = ls;
    }
    __syncthreads();
  };

  const int h = 31 - __clz(t);
  for (int bit = h - 1; bit >= 0; --bit) {
    mm(curA, curB, nxtA, nxtB);                               // square
    { short* p;
      p = curA; curA = nxtA; nxtA = p;
      p = curB; curB = nxtB; nxtB = p; }
    if ((t >> bit) & 1) {
      mm(kA, curB, nxtA, nxtB);                               // K * cur
      { short* p;
        p = curA; curA = nxtA; nxtA = p;
        p = curB; curB = nxtB; nxtB = p; }
    }
  }

  short* kt = ws + KTAB + t * KSLOT;
  for (int s = tid; s < 960; s += 256) {
    int f = s >> 6, ln = s & 63;            // f = kk*5 + nt
    int kk = f / 5, nt = f % 5;
    int k0 = kk * 32 + (ln >> 4) * 8;
    int n  = nt * 16 + (ln & 15);
    bf16x8 h8 = {}, l8 = {};
    if (k0 < 80) {
      const short* ap = curA + n * FROW + k0;
      h8 = *(const bf16x8*)ap;
      l8 = *(const bf16x8*)(ap + 96);
    }
    *(bf16x8*)(kt + f * 512 + ln * 8) = h8;
    *(bf16x8*)(kt + 7680 + f * 512 + ln * 8) = l8;
  }
}

// ---------------------------------------------------------------------------
// ypred body (256 thr): block = (bc: 128 batch rows, one t). Wave w owns
// local M-tiles {2w, 2w+1}. A hi/lo frags load DIRECTLY from the y0 frag
// table (no split8, no strided gathers); B-frags from the K^t table.
// t=0 blocks reconstruct y0 = hi + lo and copy to yp.
// ---------------------------------------------------------------------------
static __device__ __forceinline__ void ypred_body(int g, const short* __restrict__ ws,
                                                  float* __restrict__ yp, int tid) {
  const int lane = tid & 63;
  const int w    = tid >> 6;           // 0..3
  const int m16  = lane & 15;
  const int kg   = lane >> 4;
  const int bc   = g & 31;
  const int t    = g >> 5;             // 0..63
  const long b0  = (long)bc * 128;
  const short* y0f = ws + Y0F;

  if (t == 0) {
    for (int i = tid; i < 10240; i += 256) {
      const int r = i / 80, c = i - (i / 80) * 80;
      const int gmt = bc * 8 + (r >> 4);
      const int idx = ((gmt * 3 + (c >> 5)) * 64 + ((c & 31) >> 3) * 16 + (r & 15)) * 8 + (c & 7);
      yp[(b0 + r) * YROW + c] = bf2f(y0f[idx]) + bf2f(y0f[HPLANE + idx]);
    }
    return;
  }

  bf16x8 ah[2][3], al[2][3];
#pragma unroll
  for (int m = 0; m < 2; ++m) {
    const int gmt = bc * 8 + 2 * w + m;
#pragma unroll
    for (int kk = 0; kk < 3; ++kk) {
      const int idx = ((gmt * 3 + kk) * 64 + lane) * 8;
      ah[m][kk] = *(const bf16x8*)(y0f + idx);
      al[m][kk] = *(const bf16x8*)(y0f + HPLANE + idx);
    }
  }

  const short* kt = ws + KTAB + t * KSLOT;
  f32x4 acc[2][5];
#pragma unroll
  for (int m = 0; m < 2; ++m)
#pragma unroll
    for (int nt = 0; nt < 5; ++nt) acc[m][nt] = (f32x4){0.f, 0.f, 0.f, 0.f};

#pragma unroll
  for (int kk = 0; kk < 3; ++kk) {
#pragma unroll
    for (int nt = 0; nt < 5; ++nt) {
      const bf16x8 bh = *(const bf16x8*)(kt + ((kk * 5 + nt) * 64 + lane) * 8);
      const bf16x8 bl = *(const bf16x8*)(kt + 7680 + ((kk * 5 + nt) * 64 + lane) * 8);
#pragma unroll
      for (int m = 0; m < 2; ++m) {
        acc[m][nt] = MFMA(ah[m][kk], bh, acc[m][nt], 0, 0, 0);
        acc[m][nt] = MFMA(al[m][kk], bh, acc[m][nt], 0, 0, 0);
        acc[m][nt] = MFMA(ah[m][kk], bl, acc[m][nt], 0, 0, 0);
      }
    }
  }
#pragma unroll
  for (int m = 0; m < 2; ++m)
#pragma unroll
    for (int nt = 0; nt < 5; ++nt)
#pragma unroll
      for (int r = 0; r < 4; ++r)
        yp[(b0 + (2 * w + m) * 16 + kg * 4 + r) * YROW + (long)t * 80 + nt * 16 + m16] =
            acc[m][nt][r];
}

// ---------------------------------------------------------------------------
// Fused kernel: 6144 blocks. bid%3==2 -> ypred block (write-BW bound),
// else -> mlp block (latency bound); 1:2 interleave co-resides them per CU.
// ---------------------------------------------------------------------------
__global__ __launch_bounds__(256, 4) void fused_kernel(const float* __restrict__ x,
                                                       const float* __restrict__ b1g,
                                                       const float* __restrict__ b2g,
                                                       const short* __restrict__ ws,
                                                       float* __restrict__ y,
                                                       float* __restrict__ yp) {
  extern __shared__ char smem[];
  const int bid = blockIdx.x;
  const int g = bid / 3;
  const int r = bid - 3 * g;
  if (r == 2) {
    ypred_body(g, ws, yp, threadIdx.x);
  } else {
    mlp_body<16, 0>((long)(g * 2 + r), x, b1g, b2g, ws, y, nullptr,
                    (short*)smem, threadIdx.x);
  }
}

extern "C" void kernel_launch(void* const* d_in, const int* in_sizes, int n_in,
                              void* d_out, int out_size, void* d_ws, size_t ws_size,
                              hipStream_t stream) {
  const float* x  = (const float*)d_in[0];
  const float* W1 = (const float*)d_in[1];
  const float* b1 = (const float*)d_in[2];
  const float* W2 = (const float*)d_in[3];
  const float* b2 = (const float*)d_in[4];
  const float* W3 = (const float*)d_in[5];
  const float* Kg = (const float*)d_in[6];
  float* y  = (float*)d_out;
  float* yp = y + (long)NB * YROW;
  short* ws = (short*)d_ws;

  prep_kernel<<<256, 256, 0, stream>>>(W1, W2, W3, ws);
  kpow_mlp0_kernel<<<127, 256, 5 * FIMG_B, stream>>>(Kg, x, b1, b2, ws);
  fused_kernel<<<6144, 256, 64 * 264 * 2, stream>>>(x, b1, b2, ws, y, yp);
}